// Round 5
// baseline (12380.570 us; speedup 1.0000x reference)
//
#include <hip/hip_runtime.h>

namespace {

constexpr int Vv=30000, Ll=400, Bb=16, Tt=145;
constexpr int Ee=100, EHh=150, DHh=200, ENc=300;
constexpr int SOS_TOK=1;
constexpr int NB=256, NT=512;

// ---- d_out used as scratch before decoder writes it (time-disjoint) ----
constexpr long SO_EMB = 0;                      // [6400][100]
constexpr long SO_GIF = SO_EMB + 6400L*100;     // [6400][450]
constexpr long SO_GIB = SO_GIF + 6400L*450;     // [6400][450]
constexpr long SO_ENC = SO_GIB + 6400L*450;     // [6400][300]
constexpr long SO_WCAT= SO_GIF;                 // [301][300] staged after encoder

// ---- ring slot segments (floats; every offset multiple of 64 = 256B) ----
// slot t hosted at d_out + (t+2)*480000 for t<=142; t=143/144 in ws.
constexpr int RH    = 0;       // [16][200] h(t)           writer: s1
constexpr int REXP  = 3200;    // [16][400] exp-energies   writer: s2e
constexpr int RCTX  = 9600;    // [16][8][104] ctx partials writer: s2e
constexpr int RPREH = 22912;   // [16][104] h-part of pre  writer: s1
constexpr int RPSUM = 24576;   // [16][256]                writer: s4
constexpr int RPMAX = 28672;   // u64 [16][256] (8192 f)   writer: s4
constexpr int RCAND = 36864;   // [16][400][2]             writer: s4
constexpr int RING_SZ = 49664; // 198.7 KB

// ---- ws float offsets ----
constexpr long OFF_M    = 0;                    // [6400][200]
constexpr long OFF_N    = OFF_M + 6400L*200;    // [6400][100]
constexpr long OFF_Q    = OFF_N + 6400L*100;    // [6400]
constexpr long OFF_HENC = OFF_Q + 6400;         // [2dir*16][150]
constexpr long OFF_H0   = OFF_HENC + 4800;      // [16][200]
constexpr long OFF_COVER= OFF_H0 + 3200;        // [16][8][64] 256B per owner
constexpr long OFF_R143 = OFF_COVER + 8192;
constexpr long OFF_R144 = OFF_R143 + RING_SZ;
constexpr long WS_F32_END = OFF_R144 + RING_SZ; // 2,041,920 floats
constexpr long IWS_BYTE  = ((WS_F32_END*4 + 255)/256)*256;
constexpr int ISVL=0, IGV=6400, IGLS=12800, ICG0=19216, INGR=23328; // ints end 23344
constexpr long BAR_BYTE  = ((IWS_BYTE + 23344L*4 + 255)/256)*256;   // 256 ints
// bar indices
constexpr int HB_CNT=0, HB_GEN=32, EP_H=64, EP_CTX=96, EP_S4=128, EP_SET=160, ABRT=192;

struct Args {
  const int* itok;
  const float* emb;
  const float* Wfih; const float* Wfhh; const float* bfih; const float* bfhh;
  const float* Wbih; const float* Wbhh; const float* bbih; const float* bbhh;
  const float* adW; const float* adb;
  const float* dWih; const float* dWhh; const float* dbih; const float* dbhh;
  const float* bilW; const float* bilb; const float* cw;
  const float* ptrW; const float* ptrb;
  const float* preW; const float* preb; const float* outb;
  float* out; float* ws; int* iws; int* bar;
};

__device__ __forceinline__ int chunkStart(int c){ return c*117 + (c<48? c:48); }
__device__ __forceinline__ int chunkSize(int c){ return 117 + (c<48?1:0); }
__device__ __forceinline__ float sigm(float x){ return 1.f/(1.f+expf(-x)); }
__device__ __forceinline__ unsigned long long packvi(float val, int v){
  return ((unsigned long long)__float_as_uint(val)<<32) | (unsigned)(~(unsigned)v);
}
// uncached (agent-scope) producers / flag ops
__device__ __forceinline__ void ast(float* p, float v){
  __hip_atomic_store(p, v, __ATOMIC_RELAXED, __HIP_MEMORY_SCOPE_AGENT); }
__device__ __forceinline__ void astu(unsigned long long* p, unsigned long long v){
  __hip_atomic_store(p, v, __ATOMIC_RELAXED, __HIP_MEMORY_SCOPE_AGENT); }
__device__ __forceinline__ int aldi(const int* p){
  return __hip_atomic_load(p, __ATOMIC_RELAXED, __HIP_MEMORY_SCOPE_AGENT); }

__device__ __forceinline__ float* ringBase(const Args& a, int t){
  if (t<=142) return a.out + (long)(t+2)*480000;
  return a.ws + (t==143 ? OFF_R143 : OFF_R144);
}

// ---- heavy barrier with agent fences: setup phases only ----
__device__ __forceinline__ void hbar(int* bar){
  __syncthreads();
  if (threadIdx.x==0){
    int* cnt=bar+HB_CNT; int* gen=bar+HB_GEN; int* abrt=bar+ABRT;
    if (aldi(abrt)==0){
      __builtin_amdgcn_fence(__ATOMIC_RELEASE, "agent");
      int g = aldi(gen);
      int arr = __hip_atomic_fetch_add(cnt, 1, __ATOMIC_RELAXED, __HIP_MEMORY_SCOPE_AGENT);
      if (arr == NB-1){
        __hip_atomic_store(cnt, 0, __ATOMIC_RELAXED, __HIP_MEMORY_SCOPE_AGENT);
        __hip_atomic_fetch_add(gen, 1, __ATOMIC_RELEASE, __HIP_MEMORY_SCOPE_AGENT);
      } else {
        long it=0;
        while (aldi(gen) == g){
          __builtin_amdgcn_s_sleep(2);
          if (++it > 2000000L){ __hip_atomic_store(abrt,1,__ATOMIC_RELAXED,__HIP_MEMORY_SCOPE_AGENT); break; }
          if ((it&1023)==0 && aldi(abrt)!=0) break;
        }
      }
      __builtin_amdgcn_fence(__ATOMIC_ACQUIRE, "agent");
    }
  }
  __syncthreads();
}

// ---- epoch flags: monotone counters, fence-free ----
__device__ __forceinline__ void waitEp(int* ep, int target, int* abrt){
  if (threadIdx.x==0){
    if (aldi(abrt)==0){
      long it=0;
      while (aldi(ep) < target){
        if (it<32) __builtin_amdgcn_s_sleep(1); else __builtin_amdgcn_s_sleep(8);
        if (++it > 2000000L){ __hip_atomic_store(abrt,1,__ATOMIC_RELAXED,__HIP_MEMORY_SCOPE_AGENT); break; }
        if ((it&1023)==0 && aldi(abrt)!=0) break;
      }
      __builtin_amdgcn_fence(__ATOMIC_ACQUIRE, "workgroup");  // compiler ordering only
    }
  }
  __syncthreads();
}
__device__ __forceinline__ void bumpEp(int* ep){
  __syncthreads();   // compiler drains each wave's vmcnt at the barrier
  if (threadIdx.x==0){
    asm volatile("s_waitcnt vmcnt(0) lgkmcnt(0)" ::: "memory");
    __hip_atomic_fetch_add(ep, 1, __ATOMIC_RELAXED, __HIP_MEMORY_SCOPE_AGENT);
  }
}

// ---- per-b bitonic sort -> scatter group structures ----
__device__ void sortB(const Args& a, int b, char* smem){
  int tid=threadIdx.x;
  int* key=(int*)smem;
  key[tid] = (tid<Ll)? (a.itok[tid*16+b]*Ll + tid) : 0x7FFFFFFF;
  __syncthreads();
  for (int k=2;k<=512;k<<=1){
    for (int j=k>>1;j>0;j>>=1){
      int ixj = tid^j;
      if (ixj>tid){
        int x=key[tid], y=key[ixj];
        bool up = ((tid&k)==0);
        if ((x>y)==up){ key[tid]=y; key[ixj]=x; }
      }
      __syncthreads();
    }
  }
  int* ngS=(int*)(smem+2048);
  if (tid==0){
    int* svl=a.iws+ISVL+b*400; int* gvv=a.iws+IGV+b*400;
    int* gls=a.iws+IGLS+b*401;
    int ng=0, prev=-1;
    for (int i=0;i<400;i++){
      int kk=key[i]; int tok=kk/400, l=kk-tok*400;
      svl[i]=l;
      if (tok!=prev){ gvv[ng]=tok; gls[ng]=i; ng++; prev=tok; }
    }
    gls[ng]=400;
    a.iws[INGR+b]=ng;
    ngS[0]=ng;
  }
  __syncthreads();
  int ng=ngS[0];
  const int* gvv=a.iws+IGV+b*400;
  for (int c=tid;c<=256;c+=NT){
    int target=(c<256)? chunkStart(c) : 0x7FFFFFFF;
    int lo=0,hi=ng;
    while(lo<hi){ int mid=(lo+hi)>>1; if (gvv[mid]<target) lo=mid+1; else hi=mid; }
    a.iws[ICG0+b*257+c]=lo;
  }
}

// ---- LDS-tiled GEMM: MODE 0: gi ; MODE 1: M/N/Q ----
template<int MODE>
__device__ void tileGemm(const Args& a, char* smem){
  float* Xl=(float*)smem;            // [64][100]
  float* Wl=(float*)(smem+25600);    // [64][100]
  const int K   = MODE? 300 : 100;
  const int NC  = MODE? 301 : 900;
  const int nCT = MODE? 5 : 15;
  const int nTiles = 100*nCT;
  const float* X = a.out + (MODE? SO_ENC : SO_EMB);
  int ty=threadIdx.x>>4, tx=threadIdx.x&15;
  for (int tile=blockIdx.x; tile<nTiles; tile+=NB){
    int rt=tile%100, ct=tile/100;
    int r0=rt*64, c0=ct*64;
    float acc[2][4];
    #pragma unroll
    for (int i=0;i<2;i++){
      #pragma unroll
      for (int j=0;j<4;j++) acc[i][j]=0.f;
    }
    for (int k0=0;k0<K;k0+=100){
      for (int i=threadIdx.x;i<1600;i+=NT){
        int rr=i/25, e4=i%25;
        ((float4*)Xl)[rr*25+e4] = *((const float4*)(X + (long)(r0+rr)*K + k0) + e4);
      }
      for (int i=threadIdx.x;i<1600;i+=NT){
        int rr=i/25, e4=i%25; int c=c0+rr;
        float4 w={0.f,0.f,0.f,0.f};
        if (c<NC){
          const float* wr;
          if (MODE==0) wr = (c<450)? (a.Wfih + (long)c*100) : (a.Wbih + (long)(c-450)*100);
          else         wr = a.out + SO_WCAT + (long)c*300 + k0;
          w = *((const float4*)wr + e4);
        }
        ((float4*)Wl)[rr*25+e4]=w;
      }
      __syncthreads();
      for (int k4=0;k4<25;k4++){
        float4 a4[2], b4[4];
        #pragma unroll
        for (int i=0;i<2;i++) a4[i]=((float4*)Xl)[(ty*2+i)*25+k4];
        #pragma unroll
        for (int j=0;j<4;j++) b4[j]=((float4*)Wl)[(tx*4+j)*25+k4];
        #pragma unroll
        for (int i=0;i<2;i++){
          #pragma unroll
          for (int j=0;j<4;j++){
            acc[i][j] += a4[i].x*b4[j].x;
            acc[i][j] += a4[i].y*b4[j].y;
            acc[i][j] += a4[i].z*b4[j].z;
            acc[i][j] += a4[i].w*b4[j].w;
          }
        }
      }
      __syncthreads();
    }
    #pragma unroll
    for (int i=0;i<2;i++){
      #pragma unroll
      for (int j=0;j<4;j++){
        int r=r0+ty*2+i, c=c0+tx*4+j;
        if (c<NC){
          if (MODE==0){
            int dir=c/450, cc=c-dir*450;
            float v=acc[i][j] + (dir? a.bbih : a.bfih)[cc];
            a.out[(dir?SO_GIB:SO_GIF) + (long)r*450 + cc]=v;
          } else {
            if (c<200)      a.ws[OFF_M + (long)r*200 + c]=acc[i][j];
            else if (c<300) a.ws[OFF_N + (long)r*100 + (c-200)]=acc[i][j];
            else            a.ws[OFF_Q + r]=acc[i][j];
          }
        }
      }
    }
  }
}

// ---- encoder: one block per (dir,b); h in LDS, Whh slice in VGPRs ----
__device__ void encoderPhase(const Args& a, int bid, char* smem){
  int tid=threadIdx.x;
  int dir=bid>>4, b=bid&15;
  float* hbuf=(float*)smem;           // [2][192]
  float* gbuf=(float*)(smem+2048);    // [2][452]
  float* pacc=(float*)(smem+8192);    // [9][152]
  const float* Whh = dir? a.Wbhh : a.Wfhh;
  const float* bhh = dir? a.bbhh : a.bfhh;
  const float* giBase = a.out + (dir? SO_GIB : SO_GIF);
  int ks=tid/150; int j=tid-ks*150;
  bool act = (ks<3);
  float w[3][50];
  if (act){
    #pragma unroll
    for (int g=0;g<3;g++)
      for (int k=0;k<50;k++)
        w[g][k]=Whh[(long)(g*150+j)*150 + ks*50 + k];
  }
  float b0=0,b1=0,b2=0;
  if (act && ks==0){ b0=bhh[j]; b1=bhh[150+j]; b2=bhh[300+j]; }
  for (int i=tid;i<192;i+=NT) hbuf[i]=0.f;
  {
    int l0 = dir? 399 : 0;
    for (int i=tid;i<450;i+=NT) gbuf[i]=giBase[((long)l0*16+b)*450+i];
  }
  __syncthreads();
  for (int s=0;s<400;s++){
    int p=s&1;
    int l=dir? 399-s : s;
    if (tid>=450 && s+1<400){
      int ln=dir? 399-(s+1) : s+1;
      for (int i=tid-450;i<450;i+=62) gbuf[(p^1)*452+i]=giBase[((long)ln*16+b)*450+i];
    }
    if (act){
      float ar=0.f, az=0.f, an=0.f;
      const float* hr=hbuf + p*192 + ks*64;
      #pragma unroll
      for (int k4=0;k4<12;k4++){
        float4 h4=*(const float4*)(hr + k4*4);
        ar+=h4.x*w[0][k4*4+0]; ar+=h4.y*w[0][k4*4+1]; ar+=h4.z*w[0][k4*4+2]; ar+=h4.w*w[0][k4*4+3];
        az+=h4.x*w[1][k4*4+0]; az+=h4.y*w[1][k4*4+1]; az+=h4.z*w[1][k4*4+2]; az+=h4.w*w[1][k4*4+3];
        an+=h4.x*w[2][k4*4+0]; an+=h4.y*w[2][k4*4+1]; an+=h4.z*w[2][k4*4+2]; an+=h4.w*w[2][k4*4+3];
      }
      {
        float h48=hr[48], h49=hr[49];
        ar+=h48*w[0][48]+h49*w[0][49];
        az+=h48*w[1][48]+h49*w[1][49];
        an+=h48*w[2][48]+h49*w[2][49];
      }
      pacc[(ks*3+0)*152+j]=ar;
      pacc[(ks*3+1)*152+j]=az;
      pacc[(ks*3+2)*152+j]=an;
    }
    __syncthreads();
    if (act && ks==0){
      float ar=pacc[(0*3+0)*152+j]+pacc[(1*3+0)*152+j]+pacc[(2*3+0)*152+j];
      float az=pacc[(0*3+1)*152+j]+pacc[(1*3+1)*152+j]+pacc[(2*3+1)*152+j];
      float an=pacc[(0*3+2)*152+j]+pacc[(1*3+2)*152+j]+pacc[(2*3+2)*152+j];
      const float* gi=gbuf + p*452;
      float r=sigm(gi[j]      + ar + b0);
      float z=sigm(gi[150+j]  + az + b1);
      float n=tanhf(gi[300+j] + r*(an + b2));
      int slot=(j/50)*64 + (j%50);
      float hold=hbuf[p*192+slot];
      float hv=(1.f-z)*n + z*hold;
      hbuf[(p^1)*192+slot]=hv;
      a.out[SO_ENC + ((long)l*16+b)*300 + dir*150 + j]=hv;
      if (s==399) a.ws[OFF_HENC + ((long)dir*16+b)*150 + j]=hv;
    }
    __syncthreads();
  }
}

// ---- S1 (blocks 0..49): argmax(t-1) -> tok ; GRU (4 j) ; PREH (2-3 rows) ----
__device__ void s1Phase(const Args& a, int bid, int t, float* slot, const float* slotP, char* smem){
  int tid=threadIdx.x;
  float* xw=(float*)smem;             // [16][100]
  float* hw=(float*)(smem+6400);      // [16][200]
  int* tokL=(int*)(smem+19200);       // [16]
  if (t==0){
    if (tid<16) tokL[tid]=SOS_TOK;
  } else {
    const float* psum = slotP + RPSUM;
    const unsigned long long* pmax=(const unsigned long long*)(slotP + RPMAX);
    int b=tid>>5, ln=tid&31;
    float zs=0.f;
    for (int c=ln;c<256;c+=32) zs += psum[b*256+c];
    #pragma unroll
    for (int off=16;off;off>>=1) zs+=__shfl_xor(zs,off,32);
    float Z=zs;
    unsigned long long best=0;
    for (int c=ln;c<256;c+=32){
      unsigned long long pm=pmax[b*256+c];
      float ev=__uint_as_float((unsigned)(pm>>32));
      int v=(int)(~(unsigned)(pm & 0xFFFFFFFFull));
      unsigned long long pk=packvi(ev/Z, v);
      if (pk>best) best=pk;
    }
    int ng=a.iws[INGR+b];
    const float* cd=slotP + RCAND + b*800;
    const int* gvv=a.iws+IGV+b*400;
    for (int g=ln;g<ng;g+=32){
      unsigned long long pk=packvi(cd[g*2]/Z + cd[g*2+1], gvv[g]);
      if (pk>best) best=pk;
    }
    #pragma unroll
    for (int off=16;off;off>>=1){
      unsigned long long o=__shfl_xor(best,off,32);
      if (o>best) best=o;
    }
    if (ln==0) tokL[b]=(int)(~(unsigned)(best & 0xFFFFFFFFull));
  }
  __syncthreads();
  for (int i=tid;i<1600;i+=NT){ int b=i/100, e=i-b*100; xw[i]=a.emb[(long)tokL[b]*100+e]; }
  const float* hprev = (t==0)? (a.ws+OFF_H0) : (slotP+RH);
  for (int i=tid;i<3200;i+=NT) hw[i]=hprev[i];
  __syncthreads();
  {
    int pair=tid>>3, lane=tid&7;    // 64 pairs = 4 j x 16 b
    int uj=pair>>4, b=pair&15;
    int j=bid*4+uj;
    float air=0,aiz=0,ain=0,ahr=0,ahz=0,ahn=0;
    const float* x=xw+b*100;
    for (int k=lane;k<100;k+=8){
      float xv=x[k];
      air+=xv*a.dWih[(long)j*100+k];
      aiz+=xv*a.dWih[(long)(200+j)*100+k];
      ain+=xv*a.dWih[(long)(400+j)*100+k];
    }
    const float* h=hw+b*200;
    for (int k=lane;k<200;k+=8){
      float hv=h[k];
      ahr+=hv*a.dWhh[(long)j*200+k];
      ahz+=hv*a.dWhh[(long)(200+j)*200+k];
      ahn+=hv*a.dWhh[(long)(400+j)*200+k];
    }
    #pragma unroll
    for (int off=4;off;off>>=1){
      air+=__shfl_xor(air,off,8); aiz+=__shfl_xor(aiz,off,8); ain+=__shfl_xor(ain,off,8);
      ahr+=__shfl_xor(ahr,off,8); ahz+=__shfl_xor(ahz,off,8); ahn+=__shfl_xor(ahn,off,8);
    }
    if (lane==0){
      float r=sigm(air + a.dbih[j]     + ahr + a.dbhh[j]);
      float z=sigm(aiz + a.dbih[200+j] + ahz + a.dbhh[200+j]);
      float n=tanhf(ain + a.dbih[400+j] + r*(ahn + a.dbhh[400+j]));
      ast(slot + RH + b*200 + j, (1.f-z)*n + z*h[j]);
    }
  }
  // PREH rows (blocks 0..48 -> 2 rows, block 49 -> 3 incl ptr row)
  {
    int nrows=(bid==49)?3:2;
    int unit=tid>>3, lane=tid&7;    // 64 units
    int jsub=unit>>4, b=unit&15;
    if (jsub<nrows){
      int j=bid*2+jsub;
      const float* w=(j<100)? (a.preW + (long)j*500) : a.ptrW;
      const float* h=hw+b*200;
      float acc=0.f;
      for (int k=lane;k<200;k+=8) acc+=h[k]*w[k];
      #pragma unroll
      for (int off=4;off;off>>=1) acc+=__shfl_xor(acc,off,8);
      if (lane==0) ast(slot + RPREH + b*104 + j, acc);
    }
  }
}

// ---- S2e (128 blocks): energies, cover, EXPE, ctx partials (8 groups of 50 l) ----
__device__ void s2ePhase(const Args& a, int idx, int t, float* slot, const float* slotP, char* smem){
  int tid=threadIdx.x;
  int b=idx&15, lg=idx>>4, l0=lg*50;
  float* hb =(float*)smem;          // 200
  float* exl=(float*)(smem+1024);   // 50
  float* zaS=(float*)(smem+1280);   // 1
  const float* hsrc=slot + RH + b*200;
  for (int i=tid;i<200;i+=NT) hb[i]=hsrc[i];
  if (tid==0){
    float za=0.f;
    if (t>0){
      #pragma unroll
      for (int g2=0;g2<8;g2++) za += slotP[RCTX + (b*8+g2)*104 + 101];
    }
    zaS[0]=za;
  }
  __syncthreads();
  int unit=tid>>3, lane=tid&7;
  if (unit<50){
    int l=l0+unit;
    const float* Mr=a.ws+OFF_M + (long)(l*16+b)*200;
    float acc=0.f;
    for (int k=lane;k<200;k+=8) acc+=hb[k]*Mr[k];
    #pragma unroll
    for (int off=4;off;off>>=1) acc+=__shfl_xor(acc,off,8);
    if (lane==0){
      float* cov=a.ws+OFF_COVER + (b*8+lg)*64 + unit;
      float cv=*cov;
      if (t>0) cv += slotP[REXP + b*400 + l] / zaS[0];
      *cov=cv;
      float en = acc + a.bilb[0] + a.cw[0]*logf(cv + 1e-31f);
      float ex = expf(en);
      ast(slot + REXP + b*400 + l, ex);
      exl[unit]=ex;
    }
  }
  __syncthreads();
  int u2=tid>>2, lane2=tid&3;
  if (u2<102){
    int k=u2; float acc=0.f;
    if (k<100){
      for (int ll=lane2;ll<50;ll+=4) acc+=exl[ll]*a.ws[OFF_N + (long)((l0+ll)*16+b)*100 + k];
    } else if (k==100){
      for (int ll=lane2;ll<50;ll+=4) acc+=exl[ll]*a.ws[OFF_Q + (l0+ll)*16 + b];
    } else {
      for (int ll=lane2;ll<50;ll+=4) acc+=exl[ll];
    }
    #pragma unroll
    for (int off=2;off;off>>=1) acc+=__shfl_xor(acc,off,4);
    if (lane2==0) ast(slot + RCTX + (b*8+lg)*104 + k, acc);
  }
}

// ---- writeback of finalized row tr from LDS exPrev (NT stores, no atomics) ----
__device__ void wbPhase(const Args& a, int c, int tr, const float* slotP, float* exPrev, char* smem){
  int tid=threadIdx.x;
  int v0=chunkStart(c), nv=chunkSize(c);
  float* zpart=(float*)(smem+8192);   // [32][16]
  float* zl1=(float*)(smem+10240);    // 16
  float* pp1=(float*)(smem+10304);    // 16
  const float* psum = slotP + RPSUM;
  {
    int b=tid&15, seg=tid>>4;
    float z=0.f;
    for (int cc=seg;cc<256;cc+=32) z+=psum[b*256+cc];
    zpart[seg*16+b]=z;
  }
  __syncthreads();
  if (tid<16){
    int b=tid;
    float z=0.f;
    for (int s2=0;s2<32;s2++) z+=zpart[s2*16+b];
    zl1[b]=z;
    float za1=0.f, qc1=0.f;
    #pragma unroll
    for (int g2=0;g2<8;g2++){
      za1+=slotP[RCTX + (b*8+g2)*104 + 101];
      qc1+=slotP[RCTX + (b*8+g2)*104 + 100];
    }
    pp1[b]=sigm(qc1/za1 + slotP[RPREH + b*104 + 100] + a.ptrb[0]);
  }
  __syncthreads();
  if (tid<16){
    int b=tid;
    const int* cg0=a.iws+ICG0+b*257; const int* gvv=a.iws+IGV+b*400;
    const float* cd=slotP + RCAND + b*800;
    for (int g=cg0[c];g<cg0[c+1];g++){
      exPrev[(gvv[g]-v0)*17+b] += cd[g*2+1]*zl1[b];
    }
  }
  __syncthreads();
  {
    int tot=nv*16;
    for (int u=tid;u<tot;u+=NT){
      int b2=u/nv, vl=u-b2*nv;
      float sc=(1.f-pp1[b2])/zl1[b2];
      __builtin_nontemporal_store(exPrev[vl*17+b2]*sc,
                                  &a.out[((long)tr*16+b2)*30000 + v0+vl]);
    }
  }
  __syncthreads();
}

// ---- S4 (all blocks): local pre-finalize, logits+exp into LDS, psum/pmax/cand ----
__device__ void s4Phase(const Args& a, int c, int t, float* slot, float* exCur, char* smem){
  int tid=threadIdx.x;
  int v0=chunkStart(c), nv=chunkSize(c);
  float* preL=(float*)smem;           // [16][100]
  float* zaL =(float*)(smem+6400);    // 16
  float* ppqL=(float*)(smem+6464);    // 16
  if (tid<16){
    int b=tid;
    float za=0.f, qc=0.f;
    #pragma unroll
    for (int g2=0;g2<8;g2++){
      za+=slot[RCTX + (b*8+g2)*104 + 101];
      qc+=slot[RCTX + (b*8+g2)*104 + 100];
    }
    zaL[b]=za;
    ppqL[b]=sigm(qc/za + slot[RPREH + b*104 + 100] + a.ptrb[0]);
  }
  __syncthreads();
  for (int u=tid;u<1600;u+=NT){
    int b=u/100, k=u-b*100;
    float sv=0.f;
    #pragma unroll
    for (int g2=0;g2<8;g2++) sv+=slot[RCTX + (b*8+g2)*104 + k];
    preL[u]=sv/zaL[b] + slot[RPREH + b*104 + k] + a.preb[k];
  }
  __syncthreads();
  int bloc=tid&15;
  float4 preg[25];
  {
    const float4* p4=(const float4*)(preL + bloc*100);
    #pragma unroll
    for (int e4=0;e4<25;e4++) preg[e4]=p4[e4];
  }
  int nu=nv*16;
  const float4* emb4=(const float4*)a.emb;
  for (int u=tid;u<nu;u+=NT){
    int vl=u>>4; int v=v0+vl;
    float acc=a.outb[v];
    const float4* er=emb4 + (long)v*25;
    #pragma unroll
    for (int e4=0;e4<25;e4++){
      float4 A=er[e4], Bv=preg[e4];
      acc += A.x*Bv.x + A.y*Bv.y + A.z*Bv.z + A.w*Bv.w;
    }
    exCur[vl*17+bloc]=expf(acc);
  }
  __syncthreads();
  {
    int b=tid>>5, sg=tid&31;
    float s=0.f; unsigned long long m=0;
    for (int vl=sg;vl<nv;vl+=32){
      float ex=exCur[vl*17+b];
      s+=ex;
      unsigned long long pk=packvi(ex, v0+vl);
      if (pk>m) m=pk;
    }
    #pragma unroll
    for (int off=16;off;off>>=1){
      s+=__shfl_xor(s,off,32);
      unsigned long long om=__shfl_xor(m,off,32);
      if (om>m) m=om;
    }
    if (sg==0){
      ast(slot + RPSUM + b*256 + c, s);
      astu((unsigned long long*)(slot + RPMAX) + b*256 + c, m);
    }
  }
  if (tid<16){
    int b=tid;
    const int* cg0=a.iws+ICG0+b*257; const int* gvv=a.iws+IGV+b*400;
    const int* gls=a.iws+IGLS+b*401; const int* svl=a.iws+ISVL+b*400;
    float* cd=slot + RCAND + b*800;
    float pfac=ppqL[b]/(1.f-ppqL[b]);
    for (int g=cg0[c];g<cg0[c+1];g++){
      int v=gvv[g];
      float gs=0.f;
      for (int i2=gls[g];i2<gls[g+1];i2++) gs+=slot[REXP + b*400 + svl[i2]];
      ast(cd+g*2,   exCur[(v-v0)*17+b]);
      ast(cd+g*2+1, pfac*gs/zaL[b]);
    }
  }
}

__global__ void kInitBar(int* bar){
  int t=threadIdx.x;
  if (t<256) bar[t]=0;
}

__global__ __launch_bounds__(NT,1) void mega(Args a){
  __shared__ __align__(16) char smem[53248];
  int bid=blockIdx.x, tid=threadIdx.x;
  int* bar=a.bar;
  int* abrt=bar+ABRT;
  float* exBuf0=(float*)(smem+36864);   // [118][17]
  float* exBuf1=(float*)(smem+44928);

  // ---- P0a: sort (0..15) | emb gather + zero cover (16..255) ----
  if (bid<16){
    sortB(a,bid,smem);
  } else {
    for (long i=(long)(bid-16)*NT+tid; i<640000; i+=240L*NT){
      long pair=i/100; int e=(int)(i-pair*100);
      a.out[SO_EMB+i]=a.emb[(long)a.itok[pair]*100+e];
    }
    for (int i=(bid-16)*NT+tid; i<8192; i+=240*NT) a.ws[OFF_COVER+i]=0.f;
  }
  hbar(bar);

  // ---- P0b: gi GEMM ----
  tileGemm<0>(a,smem);
  hbar(bar);

  // ---- P1: encoder ----
  if (bid<32) encoderPhase(a,bid,smem);
  hbar(bar);

  // ---- P2a: stage WCAT + adapter h0 ----
  for (long i=(long)bid*NT+tid; i<90300; i+=(long)NB*NT){
    int rr=(int)(i/300), k=(int)(i-(long)rr*300);
    float v;
    if (rr<200)      v=a.bilW[(long)rr*300+k];
    else if (rr<300) v=a.preW[(long)(rr-200)*500+200+k];
    else             v=a.ptrW[200+k];
    a.out[SO_WCAT+i]=v;
  }
  if (bid>=32 && bid<48){
    int b=bid-32;
    int unit=tid>>1, lane=tid&1;
    if (unit<200){
      int j=unit;
      const float* w=a.adW+(long)j*300 + lane*150;
      const float* hh=a.ws+OFF_HENC + ((long)lane*16+b)*150;
      float acc=0.f;
      for (int e=0;e<150;e++) acc+=hh[e]*w[e];
      acc+=__shfl_xor(acc,1,2);
      if (lane==0) a.ws[OFF_H0 + b*200 + j]=acc + a.adb[j];
    }
  }
  hbar(bar);

  // ---- P2b: M/N/Q GEMM ----
  tileGemm<1>(a,smem);
  hbar(bar);                       // wb+inv: all L2s clean+invalid
  bumpEp(bar+EP_SET);              // ensure every block's inv completed
  waitEp(bar+EP_SET, NB, abrt);

  // ---- P3: decoder (flag pipeline, cached ring reads) ----
  for (int t=0;t<Tt;t++){
    int q=t&1;
    float* exCur  = q? exBuf1 : exBuf0;
    float* exPrev = q? exBuf0 : exBuf1;
    float* slot   = ringBase(a,t);
    float* slotP  = (t>0)? ringBase(a,t-1) : (float*)0;
    if (bid<50){
      waitEp(bar+EP_S4, 256*t, abrt);
      s1Phase(a,bid,t,slot,slotP,smem);
      bumpEp(bar+EP_H);
    } else if (bid>=64 && bid<192){
      waitEp(bar+EP_H, 50*(t+1), abrt);
      s2ePhase(a,bid-64,t,slot,slotP,smem);
      bumpEp(bar+EP_CTX);
    } else {
      waitEp(bar+EP_S4, 256*t, abrt);
    }
    if (t>0) wbPhase(a,bid,t-1,slotP,exPrev,smem);
    waitEp(bar+EP_CTX, 128*(t+1), abrt);
    s4Phase(a,bid,t,slot,exCur,smem);
    bumpEp(bar+EP_S4);
  }
  waitEp(bar+EP_S4, 256*Tt, abrt);
  wbPhase(a,bid,Tt-1,ringBase(a,Tt-1),((Tt-1)&1)?exBuf1:exBuf0,smem);
}

} // namespace

extern "C" void kernel_launch(void* const* d_in, const int* in_sizes, int n_in,
                              void* d_out, int out_size, void* d_ws, size_t ws_size,
                              hipStream_t stream) {
  Args a;
  a.itok=(const int*)d_in[0];
  a.emb =(const float*)d_in[1];
  a.Wfih=(const float*)d_in[2]; a.Wfhh=(const float*)d_in[3];
  a.bfih=(const float*)d_in[4]; a.bfhh=(const float*)d_in[5];
  a.Wbih=(const float*)d_in[6]; a.Wbhh=(const float*)d_in[7];
  a.bbih=(const float*)d_in[8]; a.bbhh=(const float*)d_in[9];
  a.adW =(const float*)d_in[10]; a.adb=(const float*)d_in[11];
  a.dWih=(const float*)d_in[12]; a.dWhh=(const float*)d_in[13];
  a.dbih=(const float*)d_in[14]; a.dbhh=(const float*)d_in[15];
  a.bilW=(const float*)d_in[16]; a.bilb=(const float*)d_in[17];
  a.cw  =(const float*)d_in[18];
  a.ptrW=(const float*)d_in[19]; a.ptrb=(const float*)d_in[20];
  a.preW=(const float*)d_in[21]; a.preb=(const float*)d_in[22];
  a.outb=(const float*)d_in[23];
  a.out =(float*)d_out;
  a.ws  =(float*)d_ws;
  a.iws =(int*)((char*)d_ws + IWS_BYTE);
  a.bar =(int*)((char*)d_ws + BAR_BYTE);
  // ws usage ~8.2 MB (prior rounds demonstrated >= 9.4 MB available)

  kInitBar<<<dim3(1),dim3(256),0,stream>>>(a.bar);
  void* kargs[] = { (void*)&a };
  hipLaunchCooperativeKernel(reinterpret_cast<const void*>(mega),
                             dim3(NB), dim3(NT), kargs, 0, stream);
}

// Round 6
// 11340.579 us; speedup vs baseline: 1.0917x; 1.0917x over previous
//
#include <hip/hip_runtime.h>

namespace {

constexpr int Vv=30000, Ll=400, Bb=16, Tt=145;
constexpr int Ee=100, EHh=150, DHh=200, ENc=300;
constexpr int SOS_TOK=1;
constexpr int NB=256, NT=512;

// ---- d_out used as scratch before decoder writes it (time-disjoint) ----
constexpr long SO_EMB = 0;                      // [6400][100]
constexpr long SO_GIF = SO_EMB + 6400L*100;     // [6400][450]
constexpr long SO_GIB = SO_GIF + 6400L*450;     // [6400][450]
constexpr long SO_ENC = SO_GIB + 6400L*450;     // [6400][300]
constexpr long SO_WCAT= SO_GIF;                 // [301][300] staged after encoder

// ---- ring slot segments (floats; 256B-aligned offsets) ----
// slot t hosted at d_out + (t+2)*480000 for t<=142; t=143/144 in ws.
constexpr int RH    = 0;       // [16][200] h(t)            writer: s1
constexpr int REXP  = 3200;    // [16][400] exp-energies    writer: s2e
constexpr int RCTX  = 9600;    // [16][8][104] ctx partials writer: s2e
constexpr int RPREH = 22912;   // [16][104] h-part of pre   writer: s1
constexpr int RPSUM = 24576;   // [16][256]                 writer: s4
constexpr int RPMAX = 28672;   // u64 [16][256] (8192 f)    writer: s4
constexpr int RCAND = 36864;   // [16][400][2]              writer: s4
constexpr int RING_SZ = 49664; // 198.7 KB

// ---- ws float offsets ----
constexpr long OFF_M    = 0;                    // [6400][200]
constexpr long OFF_N    = OFF_M + 6400L*200;    // [6400][100]
constexpr long OFF_Q    = OFF_N + 6400L*100;    // [6400]
constexpr long OFF_HENC = OFF_Q + 6400;         // [2dir*16][150]
constexpr long OFF_H0   = OFF_HENC + 4800;      // [16][200]
constexpr long OFF_COVER= OFF_H0 + 3200;        // [16][8][64]
constexpr long OFF_R143 = OFF_COVER + 8192;
constexpr long OFF_R144 = OFF_R143 + RING_SZ;
constexpr long WS_F32_END = OFF_R144 + RING_SZ;
constexpr long IWS_BYTE  = ((WS_F32_END*4 + 255)/256)*256;
constexpr int ISVL=0, IGV=6400, IGLS=12800, ICG0=19216, INGR=23328; // ints end 23344
constexpr long BAR_BYTE  = ((IWS_BYTE + 23344L*4 + 255)/256)*256;   // 1024 ints
// bar int indices: per-block flag arrays (NO shared-line RMW anywhere)
constexpr int FH  =0;     // [256] setup barrier flags (epochs 1..5)
constexpr int FS1 =256;   // [64]  s1 flags (50 used)
constexpr int FCTX=320;   // [128] s2e flags
constexpr int FS4 =448;   // [256] s4 flags
constexpr int ABRT=704;

struct Args {
  const int* itok;
  const float* emb;
  const float* Wfih; const float* Wfhh; const float* bfih; const float* bfhh;
  const float* Wbih; const float* Wbhh; const float* bbih; const float* bbhh;
  const float* adW; const float* adb;
  const float* dWih; const float* dWhh; const float* dbih; const float* dbhh;
  const float* bilW; const float* bilb; const float* cw;
  const float* ptrW; const float* ptrb;
  const float* preW; const float* preb; const float* outb;
  float* out; float* ws; int* iws; int* bar;
};

__device__ __forceinline__ int chunkStart(int c){ return c*117 + (c<48? c:48); }
__device__ __forceinline__ int chunkSize(int c){ return 117 + (c<48?1:0); }
__device__ __forceinline__ float sigm(float x){ return 1.f/(1.f+expf(-x)); }
__device__ __forceinline__ unsigned long long packvi(float val, int v){
  return ((unsigned long long)__float_as_uint(val)<<32) | (unsigned)(~(unsigned)v);
}
// uncached (agent-scope) accesses
__device__ __forceinline__ void ast(float* p, float v){
  __hip_atomic_store(p, v, __ATOMIC_RELAXED, __HIP_MEMORY_SCOPE_AGENT); }
__device__ __forceinline__ void astu(unsigned long long* p, unsigned long long v){
  __hip_atomic_store(p, v, __ATOMIC_RELAXED, __HIP_MEMORY_SCOPE_AGENT); }
__device__ __forceinline__ int aldi(const int* p){
  return __hip_atomic_load(p, __ATOMIC_RELAXED, __HIP_MEMORY_SCOPE_AGENT); }
__device__ __forceinline__ void asti(int* p, int v){
  __hip_atomic_store(p, v, __ATOMIC_RELAXED, __HIP_MEMORY_SCOPE_AGENT); }

__device__ __forceinline__ float* ringBase(const Args& a, int t){
  if (t<=142) return a.out + (long)(t+2)*480000;
  return a.ws + (t==143 ? OFF_R143 : OFF_R144);
}

// ---- flag sync: per-block monotone flag stores + wave-0 polled min ----
// producer side: every thread drains its own wave's stores, then thread0 flags.
__device__ __forceinline__ void setFlag(int* f, int v){
  asm volatile("s_waitcnt vmcnt(0) lgkmcnt(0)" ::: "memory");
  __syncthreads();
  if (threadIdx.x==0) asti(f, v);
}
__device__ __forceinline__ void waitFlags(const int* flags, int n, int target, int* abrt){
  if (threadIdx.x<64){
    int lane=threadIdx.x;
    long it=0;
    for (;;){
      int mn=0x7FFFFFFF;
      for (int i=lane;i<n;i+=64){
        int v=aldi(flags+i);
        if (v<mn) mn=v;
      }
      if (__all(mn>=target)) break;
      __builtin_amdgcn_s_sleep(2);
      if (++it > 400000L){ asti(abrt,1); break; }
      if ((it&255)==0 && aldi(abrt)!=0) break;
    }
  }
  __syncthreads();
}

// ---- setup barrier: flag arrival + agent fences (wbl2 / invl2) ----
__device__ __forceinline__ void hbarF(int* bar, int epoch){
  asm volatile("s_waitcnt vmcnt(0) lgkmcnt(0)" ::: "memory");
  __syncthreads();
  if (threadIdx.x==0){
    __builtin_amdgcn_fence(__ATOMIC_RELEASE, "agent");   // flush this XCD's L2
    asti(bar+FH+blockIdx.x, epoch);
  }
  waitFlags(bar+FH, NB, epoch, bar+ABRT);
  if (threadIdx.x==0)
    __builtin_amdgcn_fence(__ATOMIC_ACQUIRE, "agent");   // invalidate this XCD's L2
  __syncthreads();
}

// ---- per-b bitonic sort -> scatter group structures ----
__device__ void sortB(const Args& a, int b, char* smem){
  int tid=threadIdx.x;
  int* key=(int*)smem;
  key[tid] = (tid<Ll)? (a.itok[tid*16+b]*Ll + tid) : 0x7FFFFFFF;
  __syncthreads();
  for (int k=2;k<=512;k<<=1){
    for (int j=k>>1;j>0;j>>=1){
      int ixj = tid^j;
      if (ixj>tid){
        int x=key[tid], y=key[ixj];
        bool up = ((tid&k)==0);
        if ((x>y)==up){ key[tid]=y; key[ixj]=x; }
      }
      __syncthreads();
    }
  }
  int* ngS=(int*)(smem+2048);
  if (tid==0){
    int* svl=a.iws+ISVL+b*400; int* gvv=a.iws+IGV+b*400;
    int* gls=a.iws+IGLS+b*401;
    int ng=0, prev=-1;
    for (int i=0;i<400;i++){
      int kk=key[i]; int tok=kk/400, l=kk-tok*400;
      svl[i]=l;
      if (tok!=prev){ gvv[ng]=tok; gls[ng]=i; ng++; prev=tok; }
    }
    gls[ng]=400;
    a.iws[INGR+b]=ng;
    ngS[0]=ng;
  }
  __syncthreads();
  int ng=ngS[0];
  const int* gvv=a.iws+IGV+b*400;
  for (int c=tid;c<=256;c+=NT){
    int target=(c<256)? chunkStart(c) : 0x7FFFFFFF;
    int lo=0,hi=ng;
    while(lo<hi){ int mid=(lo+hi)>>1; if (gvv[mid]<target) lo=mid+1; else hi=mid; }
    a.iws[ICG0+b*257+c]=lo;
  }
}

// ---- LDS-tiled GEMM: MODE 0: gi ; MODE 1: M/N/Q ----
template<int MODE>
__device__ void tileGemm(const Args& a, char* smem){
  float* Xl=(float*)smem;            // [64][100]
  float* Wl=(float*)(smem+25600);    // [64][100]
  const int K   = MODE? 300 : 100;
  const int NC  = MODE? 301 : 900;
  const int nCT = MODE? 5 : 15;
  const int nTiles = 100*nCT;
  const float* X = a.out + (MODE? SO_ENC : SO_EMB);
  int ty=threadIdx.x>>4, tx=threadIdx.x&15;
  for (int tile=blockIdx.x; tile<nTiles; tile+=NB){
    int rt=tile%100, ct=tile/100;
    int r0=rt*64, c0=ct*64;
    float acc[2][4];
    #pragma unroll
    for (int i=0;i<2;i++){
      #pragma unroll
      for (int j=0;j<4;j++) acc[i][j]=0.f;
    }
    for (int k0=0;k0<K;k0+=100){
      for (int i=threadIdx.x;i<1600;i+=NT){
        int rr=i/25, e4=i%25;
        ((float4*)Xl)[rr*25+e4] = *((const float4*)(X + (long)(r0+rr)*K + k0) + e4);
      }
      for (int i=threadIdx.x;i<1600;i+=NT){
        int rr=i/25, e4=i%25; int c=c0+rr;
        float4 w={0.f,0.f,0.f,0.f};
        if (c<NC){
          const float* wr;
          if (MODE==0) wr = (c<450)? (a.Wfih + (long)c*100) : (a.Wbih + (long)(c-450)*100);
          else         wr = a.out + SO_WCAT + (long)c*300 + k0;
          w = *((const float4*)wr + e4);
        }
        ((float4*)Wl)[rr*25+e4]=w;
      }
      __syncthreads();
      for (int k4=0;k4<25;k4++){
        float4 a4[2], b4[4];
        #pragma unroll
        for (int i=0;i<2;i++) a4[i]=((float4*)Xl)[(ty*2+i)*25+k4];
        #pragma unroll
        for (int j=0;j<4;j++) b4[j]=((float4*)Wl)[(tx*4+j)*25+k4];
        #pragma unroll
        for (int i=0;i<2;i++){
          #pragma unroll
          for (int j=0;j<4;j++){
            acc[i][j] += a4[i].x*b4[j].x;
            acc[i][j] += a4[i].y*b4[j].y;
            acc[i][j] += a4[i].z*b4[j].z;
            acc[i][j] += a4[i].w*b4[j].w;
          }
        }
      }
      __syncthreads();
    }
    #pragma unroll
    for (int i=0;i<2;i++){
      #pragma unroll
      for (int j=0;j<4;j++){
        int r=r0+ty*2+i, c=c0+tx*4+j;
        if (c<NC){
          if (MODE==0){
            int dir=c/450, cc=c-dir*450;
            float v=acc[i][j] + (dir? a.bbih : a.bfih)[cc];
            a.out[(dir?SO_GIB:SO_GIF) + (long)r*450 + cc]=v;
          } else {
            if (c<200)      a.ws[OFF_M + (long)r*200 + c]=acc[i][j];
            else if (c<300) a.ws[OFF_N + (long)r*100 + (c-200)]=acc[i][j];
            else            a.ws[OFF_Q + r]=acc[i][j];
          }
        }
      }
    }
  }
}

// ---- encoder: one block per (dir,b); h in LDS, Whh slice in VGPRs ----
__device__ void encoderPhase(const Args& a, int bid, char* smem){
  int tid=threadIdx.x;
  int dir=bid>>4, b=bid&15;
  float* hbuf=(float*)smem;           // [2][192]
  float* gbuf=(float*)(smem+2048);    // [2][452]
  float* pacc=(float*)(smem+8192);    // [9][152]
  const float* Whh = dir? a.Wbhh : a.Wfhh;
  const float* bhh = dir? a.bbhh : a.bfhh;
  const float* giBase = a.out + (dir? SO_GIB : SO_GIF);
  int ks=tid/150; int j=tid-ks*150;
  bool act = (ks<3);
  float w[3][50];
  if (act){
    #pragma unroll
    for (int g=0;g<3;g++)
      for (int k=0;k<50;k++)
        w[g][k]=Whh[(long)(g*150+j)*150 + ks*50 + k];
  }
  float b0=0,b1=0,b2=0;
  if (act && ks==0){ b0=bhh[j]; b1=bhh[150+j]; b2=bhh[300+j]; }
  for (int i=tid;i<192;i+=NT) hbuf[i]=0.f;
  {
    int l0 = dir? 399 : 0;
    for (int i=tid;i<450;i+=NT) gbuf[i]=giBase[((long)l0*16+b)*450+i];
  }
  __syncthreads();
  for (int s=0;s<400;s++){
    int p=s&1;
    int l=dir? 399-s : s;
    if (tid>=450 && s+1<400){
      int ln=dir? 399-(s+1) : s+1;
      for (int i=tid-450;i<450;i+=62) gbuf[(p^1)*452+i]=giBase[((long)ln*16+b)*450+i];
    }
    if (act){
      float ar=0.f, az=0.f, an=0.f;
      const float* hr=hbuf + p*192 + ks*64;
      #pragma unroll
      for (int k4=0;k4<12;k4++){
        float4 h4=*(const float4*)(hr + k4*4);
        ar+=h4.x*w[0][k4*4+0]; ar+=h4.y*w[0][k4*4+1]; ar+=h4.z*w[0][k4*4+2]; ar+=h4.w*w[0][k4*4+3];
        az+=h4.x*w[1][k4*4+0]; az+=h4.y*w[1][k4*4+1]; az+=h4.z*w[1][k4*4+2]; az+=h4.w*w[1][k4*4+3];
        an+=h4.x*w[2][k4*4+0]; an+=h4.y*w[2][k4*4+1]; an+=h4.z*w[2][k4*4+2]; an+=h4.w*w[2][k4*4+3];
      }
      {
        float h48=hr[48], h49=hr[49];
        ar+=h48*w[0][48]+h49*w[0][49];
        az+=h48*w[1][48]+h49*w[1][49];
        an+=h48*w[2][48]+h49*w[2][49];
      }
      pacc[(ks*3+0)*152+j]=ar;
      pacc[(ks*3+1)*152+j]=az;
      pacc[(ks*3+2)*152+j]=an;
    }
    __syncthreads();
    if (act && ks==0){
      float ar=pacc[(0*3+0)*152+j]+pacc[(1*3+0)*152+j]+pacc[(2*3+0)*152+j];
      float az=pacc[(0*3+1)*152+j]+pacc[(1*3+1)*152+j]+pacc[(2*3+1)*152+j];
      float an=pacc[(0*3+2)*152+j]+pacc[(1*3+2)*152+j]+pacc[(2*3+2)*152+j];
      const float* gi=gbuf + p*452;
      float r=sigm(gi[j]      + ar + b0);
      float z=sigm(gi[150+j]  + az + b1);
      float n=tanhf(gi[300+j] + r*(an + b2));
      int slot=(j/50)*64 + (j%50);
      float hold=hbuf[p*192+slot];
      float hv=(1.f-z)*n + z*hold;
      hbuf[(p^1)*192+slot]=hv;
      a.out[SO_ENC + ((long)l*16+b)*300 + dir*150 + j]=hv;
      if (s==399) a.ws[OFF_HENC + ((long)dir*16+b)*150 + j]=hv;
    }
    __syncthreads();
  }
}

// ---- S1 (blocks 0..49): argmax(t-1) -> tok ; GRU (4 j) ; PREH (2-3 rows) ----
__device__ void s1Phase(const Args& a, int bid, int t, float* slot, const float* slotP, char* smem){
  int tid=threadIdx.x;
  float* xw=(float*)smem;             // [16][100]
  float* hw=(float*)(smem+6400);      // [16][200]
  int* tokL=(int*)(smem+19200);       // [16]
  if (t==0){
    if (tid<16) tokL[tid]=SOS_TOK;
  } else {
    const float* psum = slotP + RPSUM;
    const unsigned long long* pmax=(const unsigned long long*)(slotP + RPMAX);
    int b=tid>>5, ln=tid&31;
    float zs=0.f;
    for (int c=ln;c<256;c+=32) zs += psum[b*256+c];
    #pragma unroll
    for (int off=16;off;off>>=1) zs+=__shfl_xor(zs,off,32);
    float Z=zs;
    unsigned long long best=0;
    for (int c=ln;c<256;c+=32){
      unsigned long long pm=pmax[b*256+c];
      float ev=__uint_as_float((unsigned)(pm>>32));
      int v=(int)(~(unsigned)(pm & 0xFFFFFFFFull));
      unsigned long long pk=packvi(ev/Z, v);
      if (pk>best) best=pk;
    }
    int ng=a.iws[INGR+b];
    const float* cd=slotP + RCAND + b*800;
    const int* gvv=a.iws+IGV+b*400;
    for (int g=ln;g<ng;g+=32){
      unsigned long long pk=packvi(cd[g*2]/Z + cd[g*2+1], gvv[g]);
      if (pk>best) best=pk;
    }
    #pragma unroll
    for (int off=16;off;off>>=1){
      unsigned long long o=__shfl_xor(best,off,32);
      if (o>best) best=o;
    }
    if (ln==0) tokL[b]=(int)(~(unsigned)(best & 0xFFFFFFFFull));
  }
  __syncthreads();
  for (int i=tid;i<1600;i+=NT){ int b=i/100, e=i-b*100; xw[i]=a.emb[(long)tokL[b]*100+e]; }
  const float* hprev = (t==0)? (a.ws+OFF_H0) : (slotP+RH);
  for (int i=tid;i<3200;i+=NT) hw[i]=hprev[i];
  __syncthreads();
  {
    int pair=tid>>3, lane=tid&7;    // 64 pairs = 4 j x 16 b
    int uj=pair>>4, b=pair&15;
    int j=bid*4+uj;
    float air=0,aiz=0,ain=0,ahr=0,ahz=0,ahn=0;
    const float* x=xw+b*100;
    for (int k=lane;k<100;k+=8){
      float xv=x[k];
      air+=xv*a.dWih[(long)j*100+k];
      aiz+=xv*a.dWih[(long)(200+j)*100+k];
      ain+=xv*a.dWih[(long)(400+j)*100+k];
    }
    const float* h=hw+b*200;
    for (int k=lane;k<200;k+=8){
      float hv=h[k];
      ahr+=hv*a.dWhh[(long)j*200+k];
      ahz+=hv*a.dWhh[(long)(200+j)*200+k];
      ahn+=hv*a.dWhh[(long)(400+j)*200+k];
    }
    #pragma unroll
    for (int off=4;off;off>>=1){
      air+=__shfl_xor(air,off,8); aiz+=__shfl_xor(aiz,off,8); ain+=__shfl_xor(ain,off,8);
      ahr+=__shfl_xor(ahr,off,8); ahz+=__shfl_xor(ahz,off,8); ahn+=__shfl_xor(ahn,off,8);
    }
    if (lane==0){
      float r=sigm(air + a.dbih[j]     + ahr + a.dbhh[j]);
      float z=sigm(aiz + a.dbih[200+j] + ahz + a.dbhh[200+j]);
      float n=tanhf(ain + a.dbih[400+j] + r*(ahn + a.dbhh[400+j]));
      ast(slot + RH + b*200 + j, (1.f-z)*n + z*h[j]);
    }
  }
  // PREH rows (blocks 0..48 -> 2 rows, block 49 -> 3 incl ptr row)
  {
    int nrows=(bid==49)?3:2;
    int unit=tid>>3, lane=tid&7;
    int jsub=unit>>4, b=unit&15;
    if (jsub<nrows){
      int j=bid*2+jsub;
      const float* w=(j<100)? (a.preW + (long)j*500) : a.ptrW;
      const float* h=hw+b*200;
      float acc=0.f;
      for (int k=lane;k<200;k+=8) acc+=h[k]*w[k];
      #pragma unroll
      for (int off=4;off;off>>=1) acc+=__shfl_xor(acc,off,8);
      if (lane==0) ast(slot + RPREH + b*104 + j, acc);
    }
  }
}

// ---- S2e (128 blocks): energies, cover, EXPE, ctx partials (8 groups of 50 l) ----
__device__ void s2ePhase(const Args& a, int idx, int t, float* slot, const float* slotP, char* smem){
  int tid=threadIdx.x;
  int b=idx&15, lg=idx>>4, l0=lg*50;
  float* hb =(float*)smem;          // 200
  float* exl=(float*)(smem+1024);   // 50
  float* zaS=(float*)(smem+1280);   // 1
  const float* hsrc=slot + RH + b*200;
  for (int i=tid;i<200;i+=NT) hb[i]=hsrc[i];
  if (tid==0){
    float za=0.f;
    if (t>0){
      float s0=0,s1=0,s2=0,s3=0;
      s0=slotP[RCTX+(b*8+0)*104+101]+slotP[RCTX+(b*8+1)*104+101];
      s1=slotP[RCTX+(b*8+2)*104+101]+slotP[RCTX+(b*8+3)*104+101];
      s2=slotP[RCTX+(b*8+4)*104+101]+slotP[RCTX+(b*8+5)*104+101];
      s3=slotP[RCTX+(b*8+6)*104+101]+slotP[RCTX+(b*8+7)*104+101];
      za=(s0+s1)+(s2+s3);
    }
    zaS[0]=za;
  }
  __syncthreads();
  int unit=tid>>3, lane=tid&7;
  if (unit<50){
    int l=l0+unit;
    const float* Mr=a.ws+OFF_M + (long)(l*16+b)*200;
    float acc=0.f;
    for (int k=lane;k<200;k+=8) acc+=hb[k]*Mr[k];
    #pragma unroll
    for (int off=4;off;off>>=1) acc+=__shfl_xor(acc,off,8);
    if (lane==0){
      float* cov=a.ws+OFF_COVER + (b*8+lg)*64 + unit;
      float cv=*cov;
      if (t>0) cv += slotP[REXP + b*400 + l] / zaS[0];
      *cov=cv;
      float en = acc + a.bilb[0] + a.cw[0]*logf(cv + 1e-31f);
      float ex = expf(en);
      ast(slot + REXP + b*400 + l, ex);
      exl[unit]=ex;
    }
  }
  __syncthreads();
  int u2=tid>>2, lane2=tid&3;
  if (u2<102){
    int k=u2; float acc=0.f;
    if (k<100){
      for (int ll=lane2;ll<50;ll+=4) acc+=exl[ll]*a.ws[OFF_N + (long)((l0+ll)*16+b)*100 + k];
    } else if (k==100){
      for (int ll=lane2;ll<50;ll+=4) acc+=exl[ll]*a.ws[OFF_Q + (l0+ll)*16 + b];
    } else {
      for (int ll=lane2;ll<50;ll+=4) acc+=exl[ll];
    }
    #pragma unroll
    for (int off=2;off;off>>=1) acc+=__shfl_xor(acc,off,4);
    if (lane2==0) ast(slot + RCTX + (b*8+lg)*104 + k, acc);
  }
}

// ---- writeback of finalized row tr from LDS exPrev (NT stores, no atomics) ----
__device__ void wbPhase(const Args& a, int c, int tr, const float* slotP, float* exPrev, char* smem){
  int tid=threadIdx.x;
  int v0=chunkStart(c), nv=chunkSize(c);
  float* zpart=(float*)(smem+8192);   // [32][16]
  float* zl1=(float*)(smem+10240);    // 16
  float* pp1=(float*)(smem+10304);    // 16
  const float* psum = slotP + RPSUM;
  {
    int b=tid&15, seg=tid>>4;
    float z=0.f;
    for (int cc=seg;cc<256;cc+=32) z+=psum[b*256+cc];
    zpart[seg*16+b]=z;
  }
  __syncthreads();
  if (tid<16){
    int b=tid;
    float z=0.f;
    for (int s2=0;s2<32;s2++) z+=zpart[s2*16+b];
    zl1[b]=z;
    float za0=slotP[RCTX+(b*8+0)*104+101]+slotP[RCTX+(b*8+1)*104+101];
    float za1=slotP[RCTX+(b*8+2)*104+101]+slotP[RCTX+(b*8+3)*104+101];
    float za2=slotP[RCTX+(b*8+4)*104+101]+slotP[RCTX+(b*8+5)*104+101];
    float za3=slotP[RCTX+(b*8+6)*104+101]+slotP[RCTX+(b*8+7)*104+101];
    float qa0=slotP[RCTX+(b*8+0)*104+100]+slotP[RCTX+(b*8+1)*104+100];
    float qa1=slotP[RCTX+(b*8+2)*104+100]+slotP[RCTX+(b*8+3)*104+100];
    float qa2=slotP[RCTX+(b*8+4)*104+100]+slotP[RCTX+(b*8+5)*104+100];
    float qa3=slotP[RCTX+(b*8+6)*104+100]+slotP[RCTX+(b*8+7)*104+100];
    float za=(za0+za1)+(za2+za3);
    float qc=(qa0+qa1)+(qa2+qa3);
    pp1[b]=sigm(qc/za + slotP[RPREH + b*104 + 100] + a.ptrb[0]);
  }
  __syncthreads();
  if (tid<16){
    int b=tid;
    const int* cg0=a.iws+ICG0+b*257; const int* gvv=a.iws+IGV+b*400;
    const float* cd=slotP + RCAND + b*800;
    for (int g=cg0[c];g<cg0[c+1];g++){
      exPrev[(gvv[g]-v0)*17+b] += cd[g*2+1]*zl1[b];
    }
  }
  __syncthreads();
  {
    int tot=nv*16;
    for (int u=tid;u<tot;u+=NT){
      int b2=u/nv, vl=u-b2*nv;
      float sc=(1.f-pp1[b2])/zl1[b2];
      __builtin_nontemporal_store(exPrev[vl*17+b2]*sc,
                                  &a.out[((long)tr*16+b2)*30000 + v0+vl]);
    }
  }
  __syncthreads();
}

// ---- S4 (all blocks): local pre-finalize, logits+exp into LDS, psum/pmax/cand ----
__device__ void s4Phase(const Args& a, int c, int t, float* slot, float* exCur, char* smem){
  int tid=threadIdx.x;
  int v0=chunkStart(c), nv=chunkSize(c);
  float* preL=(float*)smem;           // [16][100]
  float* zaL =(float*)(smem+6400);    // 16
  float* ppqL=(float*)(smem+6464);    // 16
  if (tid<16){
    int b=tid;
    float za0=slot[RCTX+(b*8+0)*104+101]+slot[RCTX+(b*8+1)*104+101];
    float za1=slot[RCTX+(b*8+2)*104+101]+slot[RCTX+(b*8+3)*104+101];
    float za2=slot[RCTX+(b*8+4)*104+101]+slot[RCTX+(b*8+5)*104+101];
    float za3=slot[RCTX+(b*8+6)*104+101]+slot[RCTX+(b*8+7)*104+101];
    float qa0=slot[RCTX+(b*8+0)*104+100]+slot[RCTX+(b*8+1)*104+100];
    float qa1=slot[RCTX+(b*8+2)*104+100]+slot[RCTX+(b*8+3)*104+100];
    float qa2=slot[RCTX+(b*8+4)*104+100]+slot[RCTX+(b*8+5)*104+100];
    float qa3=slot[RCTX+(b*8+6)*104+100]+slot[RCTX+(b*8+7)*104+100];
    float za=(za0+za1)+(za2+za3);
    float qc=(qa0+qa1)+(qa2+qa3);
    zaL[b]=za;
    ppqL[b]=sigm(qc/za + slot[RPREH + b*104 + 100] + a.ptrb[0]);
  }
  __syncthreads();
  for (int u=tid;u<1600;u+=NT){
    int b=u/100, k=u-b*100;
    float s0=slot[RCTX+(b*8+0)*104+k]+slot[RCTX+(b*8+1)*104+k];
    float s1=slot[RCTX+(b*8+2)*104+k]+slot[RCTX+(b*8+3)*104+k];
    float s2=slot[RCTX+(b*8+4)*104+k]+slot[RCTX+(b*8+5)*104+k];
    float s3=slot[RCTX+(b*8+6)*104+k]+slot[RCTX+(b*8+7)*104+k];
    float sv=(s0+s1)+(s2+s3);
    preL[u]=sv/zaL[b] + slot[RPREH + b*104 + k] + a.preb[k];
  }
  __syncthreads();
  int bloc=tid&15;
  float4 preg[25];
  {
    const float4* p4=(const float4*)(preL + bloc*100);
    #pragma unroll
    for (int e4=0;e4<25;e4++) preg[e4]=p4[e4];
  }
  int nu=nv*16;
  const float4* emb4=(const float4*)a.emb;
  for (int u=tid;u<nu;u+=NT){
    int vl=u>>4; int v=v0+vl;
    float acc=a.outb[v];
    const float4* er=emb4 + (long)v*25;
    #pragma unroll
    for (int e4=0;e4<25;e4++){
      float4 A=er[e4], Bv=preg[e4];
      acc += A.x*Bv.x + A.y*Bv.y + A.z*Bv.z + A.w*Bv.w;
    }
    exCur[vl*17+bloc]=expf(acc);
  }
  __syncthreads();
  {
    int b=tid>>5, sg=tid&31;
    float s=0.f; unsigned long long m=0;
    for (int vl=sg;vl<nv;vl+=32){
      float ex=exCur[vl*17+b];
      s+=ex;
      unsigned long long pk=packvi(ex, v0+vl);
      if (pk>m) m=pk;
    }
    #pragma unroll
    for (int off=16;off;off>>=1){
      s+=__shfl_xor(s,off,32);
      unsigned long long om=__shfl_xor(m,off,32);
      if (om>m) m=om;
    }
    if (sg==0){
      ast(slot + RPSUM + b*256 + c, s);
      astu((unsigned long long*)(slot + RPMAX) + b*256 + c, m);
    }
  }
  if (tid<16){
    int b=tid;
    const int* cg0=a.iws+ICG0+b*257; const int* gvv=a.iws+IGV+b*400;
    const int* gls=a.iws+IGLS+b*401; const int* svl=a.iws+ISVL+b*400;
    float* cd=slot + RCAND + b*800;
    float pfac=ppqL[b]/(1.f-ppqL[b]);
    for (int g=cg0[c];g<cg0[c+1];g++){
      int v=gvv[g];
      float gs=0.f;
      for (int i2=gls[g];i2<gls[g+1];i2++) gs+=slot[REXP + b*400 + svl[i2]];
      ast(cd+g*2,   exCur[(v-v0)*17+b]);
      ast(cd+g*2+1, pfac*gs/zaL[b]);
    }
  }
}

__global__ void kInitBar(int* bar){
  int t=threadIdx.x;
  if (t<1024) bar[t]=0;
}

__global__ __launch_bounds__(NT,1) void mega(Args a){
  __shared__ __align__(16) char smem[53248];
  int bid=blockIdx.x, tid=threadIdx.x;
  int* bar=a.bar;
  int* abrt=bar+ABRT;
  float* exBuf0=(float*)(smem+36864);   // [118][17]
  float* exBuf1=(float*)(smem+44928);

  // ---- P0a: sort (0..15) | emb gather + zero cover (16..255) ----
  if (bid<16){
    sortB(a,bid,smem);
  } else {
    for (long i=(long)(bid-16)*NT+tid; i<640000; i+=240L*NT){
      long pair=i/100; int e=(int)(i-pair*100);
      a.out[SO_EMB+i]=a.emb[(long)a.itok[pair]*100+e];
    }
    for (int i=(bid-16)*NT+tid; i<8192; i+=240*NT) a.ws[OFF_COVER+i]=0.f;
  }
  hbarF(bar,1);

  // ---- P0b: gi GEMM ----
  tileGemm<0>(a,smem);
  hbarF(bar,2);

  // ---- P1: encoder ----
  if (bid<32) encoderPhase(a,bid,smem);
  hbarF(bar,3);

  // ---- P2a: stage WCAT + adapter h0 ----
  for (long i=(long)bid*NT+tid; i<90300; i+=(long)NB*NT){
    int rr=(int)(i/300), k=(int)(i-(long)rr*300);
    float v;
    if (rr<200)      v=a.bilW[(long)rr*300+k];
    else if (rr<300) v=a.preW[(long)(rr-200)*500+200+k];
    else             v=a.ptrW[200+k];
    a.out[SO_WCAT+i]=v;
  }
  if (bid>=32 && bid<48){
    int b=bid-32;
    int unit=tid>>1, lane=tid&1;
    if (unit<200){
      int j=unit;
      const float* w=a.adW+(long)j*300 + lane*150;
      const float* hh=a.ws+OFF_HENC + ((long)lane*16+b)*150;
      float acc=0.f;
      for (int e=0;e<150;e++) acc+=hh[e]*w[e];
      acc+=__shfl_xor(acc,1,2);
      if (lane==0) a.ws[OFF_H0 + b*200 + j]=acc + a.adb[j];
    }
  }
  hbarF(bar,4);

  // ---- P2b: M/N/Q GEMM ----
  tileGemm<1>(a,smem);
  hbarF(bar,5);   // final wb+inv: all L2s clean+invalid before flag pipeline

  // ---- P3: decoder — per-block flag pipeline, zero RMW atomics ----
  for (int t=0;t<Tt;t++){
    int q=t&1;
    float* exCur  = q? exBuf1 : exBuf0;
    float* exPrev = q? exBuf0 : exBuf1;
    float* slot   = ringBase(a,t);
    float* slotP  = (t>0)? ringBase(a,t-1) : (float*)0;
    if (bid<50){
      if (t>0) waitFlags(bar+FS4, 256, t, abrt);
      s1Phase(a,bid,t,slot,slotP,smem);
      setFlag(bar+FS1+bid, t+1);
      if (t>0) wbPhase(a,bid,t-1,slotP,exPrev,smem);
    } else if (bid>=64 && bid<192){
      waitFlags(bar+FS1, 50, t+1, abrt);
      s2ePhase(a,bid-64,t,slot,slotP,smem);
      setFlag(bar+FCTX+(bid-64), t+1);
      if (t>0) wbPhase(a,bid,t-1,slotP,exPrev,smem);
    } else {
      if (t>0){
        waitFlags(bar+FS4, 256, t, abrt);
        wbPhase(a,bid,t-1,slotP,exPrev,smem);
      }
    }
    waitFlags(bar+FCTX, 128, t+1, abrt);
    s4Phase(a,bid,t,slot,exCur,smem);
    setFlag(bar+FS4+bid, t+1);
  }
  waitFlags(bar+FS4, 256, Tt, abrt);
  wbPhase(a,bid,Tt-1,ringBase(a,Tt-1),exBuf0,smem);
}

} // namespace

extern "C" void kernel_launch(void* const* d_in, const int* in_sizes, int n_in,
                              void* d_out, int out_size, void* d_ws, size_t ws_size,
                              hipStream_t stream) {
  Args a;
  a.itok=(const int*)d_in[0];
  a.emb =(const float*)d_in[1];
  a.Wfih=(const float*)d_in[2]; a.Wfhh=(const float*)d_in[3];
  a.bfih=(const float*)d_in[4]; a.bfhh=(const float*)d_in[5];
  a.Wbih=(const float*)d_in[6]; a.Wbhh=(const float*)d_in[7];
  a.bbih=(const float*)d_in[8]; a.bbhh=(const float*)d_in[9];
  a.adW =(const float*)d_in[10]; a.adb=(const float*)d_in[11];
  a.dWih=(const float*)d_in[12]; a.dWhh=(const float*)d_in[13];
  a.dbih=(const float*)d_in[14]; a.dbhh=(const float*)d_in[15];
  a.bilW=(const float*)d_in[16]; a.bilb=(const float*)d_in[17];
  a.cw  =(const float*)d_in[18];
  a.ptrW=(const float*)d_in[19]; a.ptrb=(const float*)d_in[20];
  a.preW=(const float*)d_in[21]; a.preb=(const float*)d_in[22];
  a.outb=(const float*)d_in[23];
  a.out =(float*)d_out;
  a.ws  =(float*)d_ws;
  a.iws =(int*)((char*)d_ws + IWS_BYTE);
  a.bar =(int*)((char*)d_ws + BAR_BYTE);
  // ws usage ~8.3 MB (prior rounds demonstrated >= 9.4 MB available)

  kInitBar<<<dim3(1),dim3(1024),0,stream>>>(a.bar);
  void* kargs[] = { (void*)&a };
  hipLaunchCooperativeKernel(reinterpret_cast<const void*>(mega),
                             dim3(NB), dim3(NT), kargs, 0, stream);
}